// Round 1
// baseline (334.147 us; speedup 1.0000x reference)
//
#include <hip/hip_runtime.h>
#include <hip/hip_bf16.h>
#include <stdint.h>

// VQEmbedding: out[r] = 1.25 * ||z_r - c_argmin||^2
// z: [32768][512] f32, codebook: [8192][512] f32, out: [32768] f32
//
// ws layout (needs ~42.3 MB):
//   [0, 8MB)    codebook bf16   8192*512*2
//   [8MB, 40MB) z bf16          32768*512*2
//   [40MB, +256KB) keys f32     [2][32768] packed argmax keys (dot w/ idx in low 13 bits)

#define N_ROWS 32768
#define K_CODES 8192
#define DDIM 512

typedef __attribute__((ext_vector_type(8))) short bf16x8;
typedef __attribute__((ext_vector_type(4))) float f32x4;

__device__ __forceinline__ unsigned short f2bf(float f) {
  unsigned int u = __float_as_uint(f);
  u += 0x7FFFu + ((u >> 16) & 1u);   // RNE
  return (unsigned short)(u >> 16);
}

__global__ __launch_bounds__(256) void cvt_bf16_kernel(const float* __restrict__ in,
                                                       unsigned short* __restrict__ out,
                                                       int n8) {
  int i = blockIdx.x * 256 + threadIdx.x;
  if (i >= n8) return;
  const float4* p = (const float4*)in + (size_t)i * 2;
  float4 a = p[0], b = p[1];
  union { unsigned short us[8]; uint4 u4; } o;
  o.us[0] = f2bf(a.x); o.us[1] = f2bf(a.y); o.us[2] = f2bf(a.z); o.us[3] = f2bf(a.w);
  o.us[4] = f2bf(b.x); o.us[5] = f2bf(b.y); o.us[6] = f2bf(b.z); o.us[7] = f2bf(b.w);
  ((uint4*)out)[i] = o.u4;
}

// GEMM + fused row-argmax. grid = 512 blocks: half = bx&1 (XCD-parity -> each
// XCD L2 caches one 4MB bf16 codebook half), rb = bx>>1 (row tile of 128).
// 256 threads = 4 waves in 2x2; wave computes 64x64 via 4x4 frags of 16x16x32.
__global__ __launch_bounds__(256, 2) void gemm_argmax_kernel(
    const unsigned short* __restrict__ zb,
    const unsigned short* __restrict__ cb,
    float* __restrict__ keys) {
  __shared__ __align__(16) unsigned char sA[16384];  // 128 rows x 64 d bf16
  __shared__ __align__(16) unsigned char sB[16384];

  const int tid = threadIdx.x;
  const int w = tid >> 6, l = tid & 63;
  const int wr = w >> 1, wc = w & 1;
  const int bx = blockIdx.x;
  const int half = bx & 1, rb = bx >> 1;

  const unsigned short* Abase = zb + (size_t)rb * 128 * DDIM;
  const unsigned short* Bbase0 = cb + (size_t)half * 4096 * DDIM;

  float runkey[4][4];
#pragma unroll
  for (int m = 0; m < 4; ++m)
#pragma unroll
    for (int i = 0; i < 4; ++i) runkey[m][i] = -__builtin_inff();

  for (int ct = 0; ct < 32; ++ct) {
    const unsigned short* Bbase = Bbase0 + (size_t)ct * 128 * DDIM;
    f32x4 acc[4][4];
#pragma unroll
    for (int m = 0; m < 4; ++m)
#pragma unroll
      for (int n = 0; n < 4; ++n) acc[m][n] = (f32x4){0.f, 0.f, 0.f, 0.f};

    for (int ks = 0; ks < 8; ++ks) {
      // Stage A,B tiles: linear LDS dest (wave base + lane*16), global source
      // pre-swizzled with the same XOR the reads use (involution, G21).
#pragma unroll
      for (int q = 0; q < 4; ++q) {
        int L = (q * 256 + tid) * 16;
        int Ls = L ^ (((L >> 7) & 7) << 4);
        int e = Ls >> 1;
        int row = e >> 6, col = e & 63;
        __builtin_amdgcn_global_load_lds(
            (__attribute__((address_space(1))) void*)(Abase + (size_t)row * DDIM + ks * 64 + col),
            (__attribute__((address_space(3))) void*)(sA + (q * 256 + w * 64) * 16),
            16, 0, 0);
      }
#pragma unroll
      for (int q = 0; q < 4; ++q) {
        int L = (q * 256 + tid) * 16;
        int Ls = L ^ (((L >> 7) & 7) << 4);
        int e = Ls >> 1;
        int row = e >> 6, col = e & 63;
        __builtin_amdgcn_global_load_lds(
            (__attribute__((address_space(1))) void*)(Bbase + (size_t)row * DDIM + ks * 64 + col),
            (__attribute__((address_space(3))) void*)(sB + (q * 256 + w * 64) * 16),
            16, 0, 0);
      }
      __syncthreads();

#pragma unroll
      for (int ksub = 0; ksub < 2; ++ksub) {
        const int colbyte = ksub * 64 + (l >> 4) * 16;
        bf16x8 af[4], bfr[4];
#pragma unroll
        for (int m = 0; m < 4; ++m) {
          int r = wr * 64 + m * 16 + (l & 15);
          af[m] = *(const bf16x8*)(sA + ((r * 128 + colbyte) ^ ((r & 7) << 4)));
        }
#pragma unroll
        for (int n = 0; n < 4; ++n) {
          int r = wc * 64 + n * 16 + (l & 15);
          bfr[n] = *(const bf16x8*)(sB + ((r * 128 + colbyte) ^ ((r & 7) << 4)));
        }
#pragma unroll
        for (int m = 0; m < 4; ++m)
#pragma unroll
          for (int n = 0; n < 4; ++n)
            acc[m][n] = __builtin_amdgcn_mfma_f32_16x16x32_bf16(af[m], bfr[n], acc[m][n], 0, 0, 0);
      }
      __syncthreads();
    }

    // Fold this 128-col tile into the running argmax. C/D layout (m89/m91):
    // col = n*16 + (lane&15), row = m*16 + (lane>>4)*4 + i.
    // Key = dot with low 13 mantissa bits replaced by the global col index.
#pragma unroll
    for (int n = 0; n < 4; ++n) {
      const unsigned int col = (unsigned)(half * 4096 + ct * 128 + wc * 64 + n * 16 + (l & 15));
#pragma unroll
      for (int m = 0; m < 4; ++m)
#pragma unroll
        for (int i = 0; i < 4; ++i) {
          unsigned int u = (__float_as_uint(acc[m][n][i]) & 0xFFFFE000u) | col;
          runkey[m][i] = fmaxf(runkey[m][i], __uint_as_float(u));
        }
    }
  }

  // Reduce across the 16 lanes (same row, different col subsets), write partials.
#pragma unroll
  for (int m = 0; m < 4; ++m)
#pragma unroll
    for (int i = 0; i < 4; ++i) {
      float k = runkey[m][i];
      k = fmaxf(k, __shfl_xor(k, 1));
      k = fmaxf(k, __shfl_xor(k, 2));
      k = fmaxf(k, __shfl_xor(k, 4));
      k = fmaxf(k, __shfl_xor(k, 8));
      if ((l & 15) == 0) {
        int row = rb * 128 + wr * 64 + m * 16 + (l >> 4) * 4 + i;
        keys[half * N_ROWS + row] = k;
      }
    }
}

// One wave per row: pick winner of the two halves, gather code, exact fp32 loss.
__global__ __launch_bounds__(256) void finalize_kernel(
    const float* __restrict__ z, const float* __restrict__ cbf,
    const float* __restrict__ keys, float* __restrict__ out) {
  const int w = threadIdx.x >> 6, l = threadIdx.x & 63;
  const int row = blockIdx.x * 4 + w;
  float k = fmaxf(keys[row], keys[N_ROWS + row]);
  const int idx = (int)(__float_as_uint(k) & 8191u);
  const float* c = cbf + (size_t)idx * DDIM;
  const float* zr = z + (size_t)row * DDIM;
  float s = 0.f;
#pragma unroll
  for (int j = 0; j < 2; ++j) {
    float4 a = *(const float4*)(zr + l * 8 + j * 4);
    float4 b = *(const float4*)(c + l * 8 + j * 4);
    float dx = a.x - b.x, dy = a.y - b.y, dz = a.z - b.z, dw = a.w - b.w;
    s += dx * dx + dy * dy + dz * dz + dw * dw;
  }
  s += __shfl_xor(s, 32);
  s += __shfl_xor(s, 16);
  s += __shfl_xor(s, 8);
  s += __shfl_xor(s, 4);
  s += __shfl_xor(s, 2);
  s += __shfl_xor(s, 1);
  if (l == 0) out[row] = 1.25f * s;
}

extern "C" void kernel_launch(void* const* d_in, const int* in_sizes, int n_in,
                              void* d_out, int out_size, void* d_ws, size_t ws_size,
                              hipStream_t stream) {
  const float* z  = (const float*)d_in[0];
  const float* cb = (const float*)d_in[1];
  float* out = (float*)d_out;
  unsigned char* ws = (unsigned char*)d_ws;

  unsigned short* cb_bf = (unsigned short*)(ws);
  unsigned short* z_bf  = (unsigned short*)(ws + (size_t)8 * 1024 * 1024);
  float* keys           = (float*)(ws + (size_t)40 * 1024 * 1024);

  cvt_bf16_kernel<<<(K_CODES * DDIM) / (256 * 8), 256, 0, stream>>>(cb, cb_bf, (K_CODES * DDIM) / 8);
  cvt_bf16_kernel<<<(N_ROWS * DDIM) / (256 * 8), 256, 0, stream>>>(z, z_bf, (N_ROWS * DDIM) / 8);
  gemm_argmax_kernel<<<512, 256, 0, stream>>>(z_bf, cb_bf, keys);
  finalize_kernel<<<N_ROWS / 4, 256, 0, stream>>>(z, cb, keys, out);
}